// Round 10
// baseline (200.100 us; speedup 1.0000x reference)
//
#include <hip/hip_runtime.h>

#define NB 8
#define NN 4096
#define NS 1024
#define NC 64
#define OUT_PTS_OFF (NB*NS*3)
#define CAP 512
#define RB 0.2f
#define QPB 8

typedef __attribute__((ext_vector_type(8))) short bf16x8;
typedef __attribute__((ext_vector_type(4))) float f32x4;

static __device__ __forceinline__ short f2bf(float f){
  unsigned u = __float_as_uint(f);
  unsigned r = (u + 0x7FFFu + ((u>>16)&1u)) >> 16;
  return (short)r;
}
static __device__ __forceinline__ float bf2f(short s){
  return __uint_as_float(((unsigned)(unsigned short)s) << 16);
}
static __device__ __forceinline__ unsigned cvtpk(float a, float b){
  unsigned r;
  asm("v_cvt_pk_bf16_f32 %0, %1, %2" : "=v"(r) : "v"(a), "v"(b));
  return r;
}

// ws layout (bytes):
//   (free)                        @ 0        (1 MB)   [gsidx removed — sidx lives in LDS now]
//   float4 gxyz [8][4096]         @ 1048576  (512 KB)
//   int    cstart[8][128]         @ 1572864  (4 KB)
//   short  px1  [32768][64]       @ 2097152  (4 MB)
//   short  wf   [47104]           @ 6291456  (94 KB)
#define WS_PX1_SH   1048576   // in shorts
#define WS_WF_SH    3145728   // in shorts

// ---- fused: prep_weights (blocks 0..183) + grid_build (blocks 184..191) ----
__global__ __launch_bounds__(256) void prep_grid(
    const float* __restrict__ w0, const float* __restrict__ w1,
    const float* __restrict__ w2, short* __restrict__ ws,
    const float* __restrict__ xyz, float4* __restrict__ gxyz,
    int* __restrict__ cstart)
{
  __shared__ int hist[125];
  __shared__ int base[125];
  const int tid = threadIdx.x;

  if (blockIdx.x < 184) {
    int e = blockIdx.x*256 + tid;
    if (e >= 47104) return;
    float v = 0.f;
    if (e < 6144) {
      int j=e&7, l=(e>>3)&63, nt=(e>>9)&3, kt=e>>11;
      int k = kt*32 + ((l>>4)<<3) + j, n = nt*16 + (l&15);
      if (k < 64) v = w0[(3+k)*64 + n];
      else if (k < 67) v = w0[(k-64)*64 + n];
    } else if (e < 14336) {
      int e2=e-6144;
      int j=e2&7, l=(e2>>3)&63, nt=(e2>>9)&7, kt=e2>>12;
      int k = kt*32 + ((l>>4)<<3) + j, n = nt*16 + (l&15);
      v = w1[k*128 + n];
    } else {
      // wf2 k-relabel matches fragment-ordered h2f (R9, proven)
      int e3=e-14336;
      int j=e3&7, l=(e3>>3)&63, nt=(e3>>9)&15, kt=e3>>13;
      int k = (kt*2 + (j&1))*16 + ((l>>4)<<2) + (j>>1);
      v = w2[k*256 + nt*16 + (l&15)];
    }
    ws[e] = f2bf(v);
    return;
  }

  // ---- grid build for batch b ----
  const int b = blockIdx.x - 184;
  const float* xb = xyz + (size_t)b*NN*3;
  if (tid < 125) hist[tid] = 0;
  __syncthreads();

  float xs[16], ys[16], zs[16]; int cl[16];
  {
    const float4* xv = (const float4*)(xb + tid*48);
    #pragma unroll
    for (int g=0; g<4; ++g) {
      float4 v0 = xv[g*3], v1 = xv[g*3+1], v2 = xv[g*3+2];
      xs[g*4+0]=v0.x; xs[g*4+1]=v0.w; xs[g*4+2]=v1.z; xs[g*4+3]=v2.y;
      ys[g*4+0]=v0.y; ys[g*4+1]=v1.x; ys[g*4+2]=v1.w; ys[g*4+3]=v2.z;
      zs[g*4+0]=v0.z; zs[g*4+1]=v1.y; zs[g*4+2]=v2.x; zs[g*4+3]=v2.w;
    }
  }
  #pragma unroll
  for (int r=0; r<16; ++r) {
    int cx = min(4, (int)(xs[r]*5.0f));
    int cy = min(4, (int)(ys[r]*5.0f));
    int cz = min(4, (int)(zs[r]*5.0f));
    cl[r] = (cz*5+cy)*5+cx;
    atomicAdd(&hist[cl[r]], 1);
  }
  __syncthreads();
  if (tid == 0) {
    int acc = 0;
    for (int c=0; c<125; ++c) { base[c]=acc; cstart[b*128+c]=acc; acc+=hist[c]; }
    cstart[b*128+125] = NN;
  }
  __syncthreads();
  #pragma unroll
  for (int r=0; r<16; ++r) {
    int slot = atomicAdd(&base[cl[r]], 1);
    gxyz[b*NN + slot] = make_float4(xs[r], ys[r], zs[r], __int_as_float(tid*16+r));
  }
}

// ---- PX1[b,n,f] = ([points, xyz] @ w0_perm)[b,n,f]   (bf16, NO relu) ----
__global__ __launch_bounds__(256) void px1_kernel(
    const float* __restrict__ xyz, const float* __restrict__ points,
    const short* __restrict__ wsb, short* __restrict__ px1)
{
  const int tid = threadIdx.x;
  const int w = tid>>6, l = tid&63, lr = l&15, grp = l>>4;
  const int rowbase = blockIdx.x*64 + w*16;
  const int row = rowbase + lr;
  const float* prow = points + (size_t)row*NC;
  const float* xr   = xyz + (size_t)row*3;

  bf16x8 a0, a1, a2;
  {
    float4 u0 = *(const float4*)(prow + grp*8);
    float4 u1 = *(const float4*)(prow + grp*8 + 4);
    float4 u2 = *(const float4*)(prow + 32 + grp*8);
    float4 u3 = *(const float4*)(prow + 32 + grp*8 + 4);
    a0 = (bf16x8){f2bf(u0.x),f2bf(u0.y),f2bf(u0.z),f2bf(u0.w),f2bf(u1.x),f2bf(u1.y),f2bf(u1.z),f2bf(u1.w)};
    a1 = (bf16x8){f2bf(u2.x),f2bf(u2.y),f2bf(u2.z),f2bf(u2.w),f2bf(u3.x),f2bf(u3.y),f2bf(u3.z),f2bf(u3.w)};
    short e0=0,e1=0,e2v=0;
    if (grp==0) { e0=f2bf(xr[0]); e1=f2bf(xr[1]); e2v=f2bf(xr[2]); }
    a2 = (bf16x8){e0,e1,e2v,0,0,0,0,0};
  }
  f32x4 zero4 = {0.f,0.f,0.f,0.f};
  #pragma unroll
  for (int nt=0; nt<4; ++nt) {
    f32x4 acc = zero4;
    bf16x8 b0 = *(const bf16x8*)(wsb + (((0*4+nt)*64 + l)<<3));
    bf16x8 b1 = *(const bf16x8*)(wsb + (((1*4+nt)*64 + l)<<3));
    bf16x8 b2 = *(const bf16x8*)(wsb + (((2*4+nt)*64 + l)<<3));
    acc = __builtin_amdgcn_mfma_f32_16x16x32_bf16(a0, b0, acc, 0,0,0);
    acc = __builtin_amdgcn_mfma_f32_16x16x32_bf16(a1, b1, acc, 0,0,0);
    acc = __builtin_amdgcn_mfma_f32_16x16x32_bf16(a2, b2, acc, 0,0,0);
    #pragma unroll
    for (int i=0;i<4;++i)
      px1[(size_t)(rowbase + grp*4 + i)*64 + nt*16 + lr] = f2bf(acc[i]);
  }
}

// ---- FUSED select + MLP: QPB queries/block ----
// Select scratch overlays h2f (dead during selection). sidx/q1s stay in LDS.
// launch_bounds (256,2): DO NOT raise — (256,4) spilled b3 (R6: VGPR=64, 139us).
__global__ __launch_bounds__(256,2) void select_mlp(
    const float* __restrict__ xyz, const int* __restrict__ fps_inds,
    const float* __restrict__ w0, const short* __restrict__ wsb,
    const short* __restrict__ px1, const float4* __restrict__ gxyz,
    const int* __restrict__ cstart, float* __restrict__ out)
{
  __shared__ __align__(16) short w1s[8192];   // 16 KB
  __shared__ __align__(16) short h2f[8192];   // 16 KB; select scratch overlays
  __shared__ float q1s[QPB][64];
  __shared__ int sidx[QPB][64];
  __shared__ int scell[126];
  __shared__ int cnt_sh, T_sh;

  // overlay carve (bytes into h2f): cand_d 0..2047, cand_i 2048..4095,
  // tmp64 4096..4351, seg_s 4480.., seg_b 4608.., seg_e 4736..
  unsigned* cand_d = (unsigned*)h2f;
  int* cand_i = (int*)&h2f[1024];
  int* tmp64  = (int*)&h2f[2048];
  int* seg_s  = (int*)&h2f[2240];
  int* seg_b  = (int*)&h2f[2304];
  int* seg_e  = (int*)&h2f[2368];

  const int tid = threadIdx.x;
  const int w = tid>>6, l = tid&63, lr = l&15, grp = l>>4;
  const int q0 = blockIdx.x*QPB;
  const int b = q0 >> 10;
  const float* xb = xyz + (size_t)b*NN*3;

  // loop-invariant: layer-3 B frags (64 VGPR), latency hidden under select phase
  bf16x8 b3[4][4];
  #pragma unroll
  for (int kt=0; kt<4; ++kt)
    #pragma unroll
    for (int j=0; j<4; ++j)
      b3[kt][j] = *(const bf16x8*)(wsb + 14336 + (((kt*16 + w*4 + j)*64 + l)<<3));

  if (tid < 126) scell[tid] = cstart[b*128+tid];

  // ================= phase 1: select all QPB queries =================
  const float4* gb = gxyz + b*NN;
  for (int qq = 0; qq < QPB; ++qq) {
    const int q = q0 + qq;
    const int fps = fps_inds[q];
    const float qx = xb[fps*3+0], qy = xb[fps*3+1], qz = xb[fps*3+2];
    if (tid < 3) out[q*3+tid] = xb[fps*3+tid];
    if (tid == 0) cnt_sh = 0;

    if (tid < 32) {
      const int cx = min(4, (int)(qx*5.0f));
      const int cy = min(4, (int)(qy*5.0f));
      const int cz = min(4, (int)(qz*5.0f));
      int len = 0, s = 0;
      if (tid < 27) {
        int ncx = cx + tid%3 - 1, ncy = cy + (tid/3)%3 - 1, ncz = cz + tid/9 - 1;
        if (ncx>=0 && ncx<5 && ncy>=0 && ncy<5 && ncz>=0 && ncz<5) {
          float lox = ncx*0.2f - 1e-5f, hix = lox + 0.2f + 2e-5f;
          float loy = ncy*0.2f - 1e-5f, hiy = loy + 0.2f + 2e-5f;
          float loz = ncz*0.2f - 1e-5f, hiz = loz + 0.2f + 2e-5f;
          float dx = fmaxf(0.f, fmaxf(lox-qx, qx-hix));
          float dy = fmaxf(0.f, fmaxf(loy-qy, qy-hiy));
          float dz = fmaxf(0.f, fmaxf(loz-qz, qz-hiz));
          if (fmaf(dx,dx, fmaf(dy,dy, dz*dz)) <= 0.0402f) {
            int c = (ncz*5+ncy)*5+ncx;
            s = scell[c]; len = scell[c+1] - s;
          }
        }
      }
      int incl = len;
      #pragma unroll
      for (int off=1; off<32; off<<=1) {
        int v = __shfl_up(incl, off, 32);
        if (tid >= off) incl += v;
      }
      if (tid < 27) { seg_s[tid]=s; seg_b[tid]=incl-len; seg_e[tid]=incl; }
      if (tid == 31) T_sh = incl;
    }
    __syncthreads();   // segs + cnt ready (also fences prev query's scratch use)

    const int T = T_sh;
    {
      int k = 0;
      for (int t = tid; t < T; t += 256) {
        while (t >= seg_e[k]) ++k;
        float4 p = gb[seg_s[k] + (t - seg_b[k])];
        float fx = qx-p.x, fy = qy-p.y, fz = qz-p.z;
        float ff = fmaf(fx,fx, fmaf(fy,fy, fz*fz));
        if (ff < 0.0402f) {
          float dx=__fsub_rn(qx,p.x), dy=__fsub_rn(qy,p.y), dz=__fsub_rn(qz,p.z);
          float d2=__fadd_rn(__fadd_rn(__fmul_rn(dx,dx),__fmul_rn(dy,dy)),__fmul_rn(dz,dz));
          float d = __fsqrt_rn(d2);
          if (d < RB) {
            int pos = atomicAdd(&cnt_sh, 1);
            if (pos < CAP) { cand_d[pos] = __float_as_uint(d); cand_i[pos] = __float_as_int(p.w); }
          }
        }
      }
    }
    __syncthreads();
    int cnt = cnt_sh; if (cnt > CAP) cnt = CAP;

    if (cnt > 64) {
      for (int j=tid; j<cnt; j+=256) {
        unsigned dj = cand_d[j]; int ij = cand_i[j]; int rk = 0;
        for (int i=0; i<cnt; ++i) {
          unsigned di = cand_d[i];
          rk += (int)((di<dj) | ((di==dj) & (cand_i[i]<ij)));
        }
        if (rk < 64) tmp64[rk] = ij;
      }
      __syncthreads();
      if (tid < 64) {
        int v = tmp64[tid]; int p = 0;
        #pragma unroll
        for (int u=0; u<64; ++u) p += (tmp64[u] < v);
        sidx[qq][p] = v;
      }
    } else {
      if (tid < cnt) {
        int v = cand_i[tid]; int p = 0;
        for (int u=0; u<cnt; ++u) p += (cand_i[u] < v);
        tmp64[p] = v;
      }
      __syncthreads();
      if (tid < 64) sidx[qq][tid] = tmp64[tid < cnt ? tid : 0];
    }
    if (tid < 64) q1s[qq][tid] = qx*w0[tid] + qy*w0[64+tid] + qz*w0[128+tid];
  }
  __syncthreads();   // all sidx/q1s final; select scratch dead

  // ================= phase 2: MLP =================
  #pragma unroll
  for (int e = 0; e < 4; ++e) {
    int s = tid + e*256;
    *(bf16x8*)&w1s[s*8] = *(const bf16x8*)(wsb + 6144 + s*8);
  }
  __syncthreads();

  const short* px1b = px1 + (size_t)b*NN*64;
  const int myrow = w*16 + lr;

  bf16x8 v0, v1;
  {
    int idx = sidx[0][myrow];
    v0 = *(const bf16x8*)(px1b + idx*64 + grp*8);
    v1 = *(const bf16x8*)(px1b + idx*64 + 32 + grp*8);
  }

  f32x4 zero4 = {0.f,0.f,0.f,0.f};
  const int uu4 = (lr>>2) << 4;     // write-side XOR (byte bits 4-5)
  const int gg4 = grp << 4;         // read-side XOR

  for (int qq = 0; qq < QPB; ++qq) {
    if (qq) __syncthreads();

    bf16x8 a20, a21;
    {
      union { unsigned u[4]; bf16x8 v; } ua, ub;
      #pragma unroll
      for (int jp=0; jp<4; ++jp) {
        float x0 = fmaxf(bf2f(v0[2*jp  ]) - q1s[qq][grp*8+2*jp  ], 0.f);
        float x1 = fmaxf(bf2f(v0[2*jp+1]) - q1s[qq][grp*8+2*jp+1], 0.f);
        ua.u[jp] = cvtpk(x0, x1);
        float y0 = fmaxf(bf2f(v1[2*jp  ]) - q1s[qq][32+grp*8+2*jp  ], 0.f);
        float y1 = fmaxf(bf2f(v1[2*jp+1]) - q1s[qq][32+grp*8+2*jp+1], 0.f);
        ub.u[jp] = cvtpk(y0, y1);
      }
      a20 = ua.v; a21 = ub.v;
    }
    if (qq+1 < QPB) {
      int idx = sidx[qq+1][myrow];
      v0 = *(const bf16x8*)(px1b + idx*64 + grp*8);
      v1 = *(const bf16x8*)(px1b + idx*64 + 32 + grp*8);
    }

    // layer 2: B from LDS; packed b32 stores into fragment-ordered h2f
    #pragma unroll
    for (int ntp=0; ntp<4; ++ntp) {
      f32x4 accA = zero4, accB = zero4;
      bf16x8 bA0 = *(const bf16x8*)&w1s[((0*8 + 2*ntp  )*64 + l)*8];
      bf16x8 bA1 = *(const bf16x8*)&w1s[((1*8 + 2*ntp  )*64 + l)*8];
      bf16x8 bB0 = *(const bf16x8*)&w1s[((0*8 + 2*ntp+1)*64 + l)*8];
      bf16x8 bB1 = *(const bf16x8*)&w1s[((1*8 + 2*ntp+1)*64 + l)*8];
      accA = __builtin_amdgcn_mfma_f32_16x16x32_bf16(a20, bA0, accA, 0,0,0);
      accA = __builtin_amdgcn_mfma_f32_16x16x32_bf16(a21, bA1, accA, 0,0,0);
      accB = __builtin_amdgcn_mfma_f32_16x16x32_bf16(a20, bB0, accB, 0,0,0);
      accB = __builtin_amdgcn_mfma_f32_16x16x32_bf16(a21, bB1, accB, 0,0,0);
      #pragma unroll
      for (int i=0; i<4; ++i) {
        unsigned pv = cvtpk(fmaxf(accA[i],0.f), fmaxf(accB[i],0.f));
        int byteoff = ((((w*4+ntp)*64 + (lr>>2)*16 + grp*4 + i)<<4) + ((lr&3)<<2)) ^ uu4;
        *(unsigned*)((char*)h2f + byteoff) = pv;
      }
    }
    __syncthreads();

    // layer 3: running-max over mt (acc3 64 regs -> acc 16 + rm 16)
    float rm[4][4];
    #pragma unroll
    for (int j=0;j<4;++j)
      #pragma unroll
      for (int i=0;i<4;++i) rm[j][i] = 0.f;   // relu folded in
    #pragma unroll
    for (int mt=0; mt<4; ++mt) {
      f32x4 acc[4] = {zero4, zero4, zero4, zero4};
      #pragma unroll
      for (int kt=0; kt<4; ++kt) {
        int byteoff = ((((mt*4+kt)*64 + l)<<4)) ^ gg4;
        bf16x8 a = *(const bf16x8*)((const char*)h2f + byteoff);
        #pragma unroll
        for (int j=0; j<4; ++j)
          acc[j] = __builtin_amdgcn_mfma_f32_16x16x32_bf16(a, b3[kt][j], acc[j], 0,0,0);
      }
      #pragma unroll
      for (int j=0; j<4; ++j)
        #pragma unroll
        for (int i=0; i<4; ++i) rm[j][i] = fmaxf(rm[j][i], acc[j][i]);
    }
    #pragma unroll
    for (int j=0; j<4; ++j) {
      float m = fmaxf(fmaxf(rm[j][0],rm[j][1]), fmaxf(rm[j][2],rm[j][3]));
      m = fmaxf(m, __shfl_xor(m, 16, 64));
      m = fmaxf(m, __shfl_xor(m, 32, 64));
      if (grp == 0) out[OUT_PTS_OFF + (q0+qq)*256 + (w*4+j)*16 + lr] = m;
    }
  }
}

extern "C" void kernel_launch(void* const* d_in, const int* in_sizes, int n_in,
                              void* d_out, int out_size, void* d_ws, size_t ws_size,
                              hipStream_t stream) {
  const float* xyz      = (const float*)d_in[0];
  const float* points   = (const float*)d_in[1];
  const int*   fps_inds = (const int*)d_in[2];
  const float* w0       = (const float*)d_in[3];
  const float* w1       = (const float*)d_in[4];
  const float* w2       = (const float*)d_in[5];
  float* out = (float*)d_out;

  float4* gxyz  = (float4*)((char*)d_ws + 1048576);
  int*    cstart= (int*)((char*)d_ws + 1572864);
  short*  px1   = (short*)d_ws + WS_PX1_SH;
  short*  wsb   = (short*)d_ws + WS_WF_SH;

  hipLaunchKernelGGL(prep_grid,  dim3(192), dim3(256), 0, stream,
                     w0, w1, w2, wsb, xyz, gxyz, cstart);
  hipLaunchKernelGGL(px1_kernel, dim3(512), dim3(256), 0, stream, xyz, points, wsb, px1);
  hipLaunchKernelGGL(select_mlp, dim3(NB*NS/QPB), dim3(256), 0, stream,
                     xyz, fps_inds, w0, wsb, px1, gxyz, cstart, out);
}

// Round 11
// 106.001 us; speedup vs baseline: 1.8877x; 1.8877x over previous
//
#include <hip/hip_runtime.h>

#define NB 8
#define NN 4096
#define NS 1024
#define NC 64
#define OUT_PTS_OFF (NB*NS*3)
#define CAP 512
#define RB 0.2f
#define QPB 4

typedef __attribute__((ext_vector_type(8))) short bf16x8;
typedef __attribute__((ext_vector_type(4))) float f32x4;

static __device__ __forceinline__ short f2bf(float f){
  unsigned u = __float_as_uint(f);
  unsigned r = (u + 0x7FFFu + ((u>>16)&1u)) >> 16;
  return (short)r;
}
static __device__ __forceinline__ float bf2f(short s){
  return __uint_as_float(((unsigned)(unsigned short)s) << 16);
}
static __device__ __forceinline__ unsigned cvtpk(float a, float b){
  unsigned r;
  asm("v_cvt_pk_bf16_f32 %0, %1, %2" : "=v"(r) : "v"(a), "v"(b));
  return r;
}

// ws layout (bytes):
//   ushort gsidx[8192][64]        @ 0        (1 MB)
//   float4 gxyz [8][4096]         @ 1048576  (512 KB)
//   int    cstart[8][128]         @ 1572864  (4 KB)
//   short  px1  [32768][64]       @ 2097152  (4 MB)
//   short  wf   [47104]           @ 6291456  (94 KB)
#define WS_PX1_SH   1048576   // in shorts
#define WS_WF_SH    3145728   // in shorts

// ---- fused: prep_weights (blocks 0..183) + grid_build (blocks 184..191) ----
__global__ __launch_bounds__(256) void prep_grid(
    const float* __restrict__ w0, const float* __restrict__ w1,
    const float* __restrict__ w2, short* __restrict__ ws,
    const float* __restrict__ xyz, float4* __restrict__ gxyz,
    int* __restrict__ cstart)
{
  __shared__ int hist[125];
  __shared__ int base[125];
  const int tid = threadIdx.x;

  if (blockIdx.x < 184) {
    int e = blockIdx.x*256 + tid;
    if (e >= 47104) return;
    float v = 0.f;
    if (e < 6144) {
      int j=e&7, l=(e>>3)&63, nt=(e>>9)&3, kt=e>>11;
      int k = kt*32 + ((l>>4)<<3) + j, n = nt*16 + (l&15);
      if (k < 64) v = w0[(3+k)*64 + n];
      else if (k < 67) v = w0[(k-64)*64 + n];
    } else if (e < 14336) {
      int e2=e-6144;
      int j=e2&7, l=(e2>>3)&63, nt=(e2>>9)&7, kt=e2>>12;
      int k = kt*32 + ((l>>4)<<3) + j, n = nt*16 + (l&15);
      v = w1[k*128 + n];
    } else {
      // wf2 k-relabel matches fragment-ordered h2f (R9, proven)
      int e3=e-14336;
      int j=e3&7, l=(e3>>3)&63, nt=(e3>>9)&15, kt=e3>>13;
      int k = (kt*2 + (j&1))*16 + ((l>>4)<<2) + (j>>1);
      v = w2[k*256 + nt*16 + (l&15)];
    }
    ws[e] = f2bf(v);
    return;
  }

  const int b = blockIdx.x - 184;
  const float* xb = xyz + (size_t)b*NN*3;
  if (tid < 125) hist[tid] = 0;
  __syncthreads();

  float xs[16], ys[16], zs[16]; int cl[16];
  {
    const float4* xv = (const float4*)(xb + tid*48);
    #pragma unroll
    for (int g=0; g<4; ++g) {
      float4 v0 = xv[g*3], v1 = xv[g*3+1], v2 = xv[g*3+2];
      xs[g*4+0]=v0.x; xs[g*4+1]=v0.w; xs[g*4+2]=v1.z; xs[g*4+3]=v2.y;
      ys[g*4+0]=v0.y; ys[g*4+1]=v1.x; ys[g*4+2]=v1.w; ys[g*4+3]=v2.z;
      zs[g*4+0]=v0.z; zs[g*4+1]=v1.y; zs[g*4+2]=v2.x; zs[g*4+3]=v2.w;
    }
  }
  #pragma unroll
  for (int r=0; r<16; ++r) {
    int cx = min(4, (int)(xs[r]*5.0f));
    int cy = min(4, (int)(ys[r]*5.0f));
    int cz = min(4, (int)(zs[r]*5.0f));
    cl[r] = (cz*5+cy)*5+cx;
    atomicAdd(&hist[cl[r]], 1);
  }
  __syncthreads();
  if (tid == 0) {
    int acc = 0;
    for (int c=0; c<125; ++c) { base[c]=acc; cstart[b*128+c]=acc; acc+=hist[c]; }
    cstart[b*128+125] = NN;
  }
  __syncthreads();
  #pragma unroll
  for (int r=0; r<16; ++r) {
    int slot = atomicAdd(&base[cl[r]], 1);
    gxyz[b*NN + slot] = make_float4(xs[r], ys[r], zs[r], __int_as_float(tid*16+r));
  }
}

// ---- fused px1 (blocks 0..511) + select (blocks 512..8703) ----
__global__ __launch_bounds__(256) void px1_select(
    const float* __restrict__ xyz, const float* __restrict__ points,
    const int* __restrict__ fps_inds, const short* __restrict__ wsb,
    const float4* __restrict__ gxyz, const int* __restrict__ cstart,
    short* __restrict__ px1, unsigned short* __restrict__ gsidx,
    float* __restrict__ out)
{
  __shared__ unsigned int cand_d[CAP];
  __shared__ int cand_i[CAP];
  __shared__ int scell[126];
  __shared__ int seg_s[27], seg_b[27], seg_e[27];
  __shared__ int tmp64[64];
  __shared__ int cnt_sh, T_sh;

  const int tid = threadIdx.x;

  if (blockIdx.x < 512) {
    // ---------------- px1: 64 rows per block ----------------
    const int w = tid>>6, l = tid&63, lr = l&15, grp = l>>4;
    const int rowbase = blockIdx.x*64 + w*16;
    const int row = rowbase + lr;
    const float* prow = points + (size_t)row*NC;
    const float* xr   = xyz + (size_t)row*3;

    bf16x8 a0, a1, a2;
    {
      float4 u0 = *(const float4*)(prow + grp*8);
      float4 u1 = *(const float4*)(prow + grp*8 + 4);
      float4 u2 = *(const float4*)(prow + 32 + grp*8);
      float4 u3 = *(const float4*)(prow + 32 + grp*8 + 4);
      a0 = (bf16x8){f2bf(u0.x),f2bf(u0.y),f2bf(u0.z),f2bf(u0.w),f2bf(u1.x),f2bf(u1.y),f2bf(u1.z),f2bf(u1.w)};
      a1 = (bf16x8){f2bf(u2.x),f2bf(u2.y),f2bf(u2.z),f2bf(u2.w),f2bf(u3.x),f2bf(u3.y),f2bf(u3.z),f2bf(u3.w)};
      short e0=0,e1=0,e2v=0;
      if (grp==0) { e0=f2bf(xr[0]); e1=f2bf(xr[1]); e2v=f2bf(xr[2]); }
      a2 = (bf16x8){e0,e1,e2v,0,0,0,0,0};
    }
    f32x4 zero4 = {0.f,0.f,0.f,0.f};
    #pragma unroll
    for (int nt=0; nt<4; ++nt) {
      f32x4 acc = zero4;
      bf16x8 b0 = *(const bf16x8*)(wsb + (((0*4+nt)*64 + l)<<3));
      bf16x8 b1 = *(const bf16x8*)(wsb + (((1*4+nt)*64 + l)<<3));
      bf16x8 b2 = *(const bf16x8*)(wsb + (((2*4+nt)*64 + l)<<3));
      acc = __builtin_amdgcn_mfma_f32_16x16x32_bf16(a0, b0, acc, 0,0,0);
      acc = __builtin_amdgcn_mfma_f32_16x16x32_bf16(a1, b1, acc, 0,0,0);
      acc = __builtin_amdgcn_mfma_f32_16x16x32_bf16(a2, b2, acc, 0,0,0);
      #pragma unroll
      for (int i=0;i<4;++i)
        px1[(size_t)(rowbase + grp*4 + i)*64 + nt*16 + lr] = f2bf(acc[i]);
    }
    return;
  }

  // ---------------- select: 1 query per block ----------------
  const int q = blockIdx.x - 512, b = q >> 10;
  const float* xb = xyz + (size_t)b*NN*3;
  const int fps = fps_inds[q];
  const float qx = xb[fps*3+0], qy = xb[fps*3+1], qz = xb[fps*3+2];
  if (tid < 3) out[q*3+tid] = xb[fps*3+tid];
  if (tid < 126) scell[tid] = cstart[b*128+tid];
  if (tid == 0) cnt_sh = 0;
  __syncthreads();

  if (tid < 32) {
    const int cx = min(4, (int)(qx*5.0f));
    const int cy = min(4, (int)(qy*5.0f));
    const int cz = min(4, (int)(qz*5.0f));
    int len = 0, s = 0;
    if (tid < 27) {
      int ncx = cx + tid%3 - 1, ncy = cy + (tid/3)%3 - 1, ncz = cz + tid/9 - 1;
      if (ncx>=0 && ncx<5 && ncy>=0 && ncy<5 && ncz>=0 && ncz<5) {
        float lox = ncx*0.2f - 1e-5f, hix = lox + 0.2f + 2e-5f;
        float loy = ncy*0.2f - 1e-5f, hiy = loy + 0.2f + 2e-5f;
        float loz = ncz*0.2f - 1e-5f, hiz = loz + 0.2f + 2e-5f;
        float dx = fmaxf(0.f, fmaxf(lox-qx, qx-hix));
        float dy = fmaxf(0.f, fmaxf(loy-qy, qy-hiy));
        float dz = fmaxf(0.f, fmaxf(loz-qz, qz-hiz));
        if (fmaf(dx,dx, fmaf(dy,dy, dz*dz)) <= 0.0402f) {
          int c = (ncz*5+ncy)*5+ncx;
          s = scell[c]; len = scell[c+1] - s;
        }
      }
    }
    int incl = len;
    #pragma unroll
    for (int off=1; off<32; off<<=1) {
      int v = __shfl_up(incl, off, 32);
      if (tid >= off) incl += v;
    }
    if (tid < 27) { seg_s[tid]=s; seg_b[tid]=incl-len; seg_e[tid]=incl; }
    if (tid == 31) T_sh = incl;
  }
  __syncthreads();

  const int T = T_sh;
  const float4* gb = gxyz + b*NN;
  {
    int k = 0;
    for (int t = tid; t < T; t += 256) {
      while (t >= seg_e[k]) ++k;
      float4 p = gb[seg_s[k] + (t - seg_b[k])];
      float fx = qx-p.x, fy = qy-p.y, fz = qz-p.z;
      float ff = fmaf(fx,fx, fmaf(fy,fy, fz*fz));
      if (ff < 0.0402f) {
        float dx=__fsub_rn(qx,p.x), dy=__fsub_rn(qy,p.y), dz=__fsub_rn(qz,p.z);
        float d2=__fadd_rn(__fadd_rn(__fmul_rn(dx,dx),__fmul_rn(dy,dy)),__fmul_rn(dz,dz));
        float d = __fsqrt_rn(d2);
        if (d < RB) {
          int pos = atomicAdd(&cnt_sh, 1);
          if (pos < CAP) { cand_d[pos] = __float_as_uint(d); cand_i[pos] = __float_as_int(p.w); }
        }
      }
    }
  }
  __syncthreads();
  int cnt = cnt_sh; if (cnt > CAP) cnt = CAP;

  if (cnt > 64) {
    for (int j=tid; j<cnt; j+=256) {
      unsigned dj = cand_d[j]; int ij = cand_i[j]; int rk = 0;
      for (int i=0; i<cnt; ++i) {
        unsigned di = cand_d[i];
        rk += (int)((di<dj) | ((di==dj) & (cand_i[i]<ij)));
      }
      if (rk < 64) tmp64[rk] = ij;
    }
    __syncthreads();
    if (tid < 64) {
      int v = tmp64[tid]; int p = 0;
      #pragma unroll
      for (int u=0; u<64; ++u) p += (tmp64[u] < v);
      gsidx[q*64 + p] = (unsigned short)v;
    }
  } else {
    if (tid < cnt) {
      int v = cand_i[tid]; int p = 0;
      for (int u=0; u<cnt; ++u) p += (cand_i[u] < v);
      tmp64[p] = v;
    }
    __syncthreads();
    if (tid < 64) gsidx[q*64 + tid] = (unsigned short)tmp64[tid < cnt ? tid : 0];
  }
}

// ---- MLP: persistent QPB queries/block; wf2 in regs, wf1 in LDS (R9 proven) ----
// QPB=4 / grid 2048: 2 rounds of resident blocks -> cross-block pipelining.
// launch_bounds (256,2): DO NOT raise — (256,4) spilled b3 (R6: VGPR=64, 139us).
__global__ __launch_bounds__(256,2) void mlp_kernel(
    const float* __restrict__ xyz, const int* __restrict__ fps_inds,
    const float* __restrict__ w0, const short* __restrict__ wsb,
    const short* __restrict__ px1, const unsigned short* __restrict__ gsidx,
    float* __restrict__ out)
{
  __shared__ __align__(16) short w1s[8192];   // 16 KB
  __shared__ __align__(16) short h2f[8192];   // 16 KB, fragment-ordered
  __shared__ float q1s[QPB][64];
  __shared__ int sidx[QPB][64];

  const int tid = threadIdx.x;
  const int w = tid>>6, l = tid&63, lr = l&15, grp = l>>4;
  const int q0 = blockIdx.x*QPB;
  const int b = q0 >> 10;
  const float* xb = xyz + (size_t)b*NN*3;

  bf16x8 b3[4][4];
  #pragma unroll
  for (int kt=0; kt<4; ++kt)
    #pragma unroll
    for (int j=0; j<4; ++j)
      b3[kt][j] = *(const bf16x8*)(wsb + 14336 + (((kt*16 + w*4 + j)*64 + l)<<3));

  #pragma unroll
  for (int e = 0; e < 4; ++e) {
    int s = tid + e*256;
    *(bf16x8*)&w1s[s*8] = *(const bf16x8*)(wsb + 6144 + s*8);
  }
  {
    int qq = tid>>6, t = tid&63;   // 256 threads = QPB*64 exactly
    int fp = fps_inds[q0+qq];
    sidx[qq][t] = (int)gsidx[(q0+qq)*64 + t];
    q1s[qq][t] = xb[fp*3]*w0[t] + xb[fp*3+1]*w0[64+t] + xb[fp*3+2]*w0[128+t];
  }
  if (tid < QPB*3) {
    int qq = tid/3, c = tid - qq*3;
    int fp = fps_inds[q0+qq];
    out[(q0+qq)*3 + c] = xb[fp*3+c];
  }
  __syncthreads();

  const short* px1b = px1 + (size_t)b*NN*64;
  const int myrow = w*16 + lr;

  bf16x8 v0, v1;
  {
    int idx = sidx[0][myrow];
    v0 = *(const bf16x8*)(px1b + idx*64 + grp*8);
    v1 = *(const bf16x8*)(px1b + idx*64 + 32 + grp*8);
  }

  f32x4 zero4 = {0.f,0.f,0.f,0.f};
  const int uu4 = (lr>>2) << 4;     // write-side XOR (byte bits 4-5)
  const int gg4 = grp << 4;         // read-side XOR

  for (int qq = 0; qq < QPB; ++qq) {
    if (qq) __syncthreads();

    bf16x8 a20, a21;
    {
      union { unsigned u[4]; bf16x8 v; } ua, ub;
      #pragma unroll
      for (int jp=0; jp<4; ++jp) {
        float x0 = fmaxf(bf2f(v0[2*jp  ]) - q1s[qq][grp*8+2*jp  ], 0.f);
        float x1 = fmaxf(bf2f(v0[2*jp+1]) - q1s[qq][grp*8+2*jp+1], 0.f);
        ua.u[jp] = cvtpk(x0, x1);
        float y0 = fmaxf(bf2f(v1[2*jp  ]) - q1s[qq][32+grp*8+2*jp  ], 0.f);
        float y1 = fmaxf(bf2f(v1[2*jp+1]) - q1s[qq][32+grp*8+2*jp+1], 0.f);
        ub.u[jp] = cvtpk(y0, y1);
      }
      a20 = ua.v; a21 = ub.v;
    }
    if (qq+1 < QPB) {
      int idx = sidx[qq+1][myrow];
      v0 = *(const bf16x8*)(px1b + idx*64 + grp*8);
      v1 = *(const bf16x8*)(px1b + idx*64 + 32 + grp*8);
    }

    #pragma unroll
    for (int ntp=0; ntp<4; ++ntp) {
      f32x4 accA = zero4, accB = zero4;
      bf16x8 bA0 = *(const bf16x8*)&w1s[((0*8 + 2*ntp  )*64 + l)*8];
      bf16x8 bA1 = *(const bf16x8*)&w1s[((1*8 + 2*ntp  )*64 + l)*8];
      bf16x8 bB0 = *(const bf16x8*)&w1s[((0*8 + 2*ntp+1)*64 + l)*8];
      bf16x8 bB1 = *(const bf16x8*)&w1s[((1*8 + 2*ntp+1)*64 + l)*8];
      accA = __builtin_amdgcn_mfma_f32_16x16x32_bf16(a20, bA0, accA, 0,0,0);
      accA = __builtin_amdgcn_mfma_f32_16x16x32_bf16(a21, bA1, accA, 0,0,0);
      accB = __builtin_amdgcn_mfma_f32_16x16x32_bf16(a20, bB0, accB, 0,0,0);
      accB = __builtin_amdgcn_mfma_f32_16x16x32_bf16(a21, bB1, accB, 0,0,0);
      #pragma unroll
      for (int i=0; i<4; ++i) {
        unsigned pv = cvtpk(fmaxf(accA[i],0.f), fmaxf(accB[i],0.f));
        int byteoff = ((((w*4+ntp)*64 + (lr>>2)*16 + grp*4 + i)<<4) + ((lr&3)<<2)) ^ uu4;
        *(unsigned*)((char*)h2f + byteoff) = pv;
      }
    }
    __syncthreads();

    // layer 3: running-max over mt
    float rm[4][4];
    #pragma unroll
    for (int j=0;j<4;++j)
      #pragma unroll
      for (int i=0;i<4;++i) rm[j][i] = 0.f;
    #pragma unroll
    for (int mt=0; mt<4; ++mt) {
      f32x4 acc[4] = {zero4, zero4, zero4, zero4};
      #pragma unroll
      for (int kt=0; kt<4; ++kt) {
        int byteoff = ((((mt*4+kt)*64 + l)<<4)) ^ gg4;
        bf16x8 a = *(const bf16x8*)((const char*)h2f + byteoff);
        #pragma unroll
        for (int j=0; j<4; ++j)
          acc[j] = __builtin_amdgcn_mfma_f32_16x16x32_bf16(a, b3[kt][j], acc[j], 0,0,0);
      }
      #pragma unroll
      for (int j=0; j<4; ++j)
        #pragma unroll
        for (int i=0; i<4; ++i) rm[j][i] = fmaxf(rm[j][i], acc[j][i]);
    }
    #pragma unroll
    for (int j=0; j<4; ++j) {
      float m = fmaxf(fmaxf(rm[j][0],rm[j][1]), fmaxf(rm[j][2],rm[j][3]));
      m = fmaxf(m, __shfl_xor(m, 16, 64));
      m = fmaxf(m, __shfl_xor(m, 32, 64));
      if (grp == 0) out[OUT_PTS_OFF + (q0+qq)*256 + (w*4+j)*16 + lr] = m;
    }
  }
}

extern "C" void kernel_launch(void* const* d_in, const int* in_sizes, int n_in,
                              void* d_out, int out_size, void* d_ws, size_t ws_size,
                              hipStream_t stream) {
  const float* xyz      = (const float*)d_in[0];
  const float* points   = (const float*)d_in[1];
  const int*   fps_inds = (const int*)d_in[2];
  const float* w0       = (const float*)d_in[3];
  const float* w1       = (const float*)d_in[4];
  const float* w2       = (const float*)d_in[5];
  float* out = (float*)d_out;

  unsigned short* gsidx = (unsigned short*)d_ws;
  float4* gxyz  = (float4*)((char*)d_ws + 1048576);
  int*    cstart= (int*)((char*)d_ws + 1572864);
  short*  px1   = (short*)d_ws + WS_PX1_SH;
  short*  wsb   = (short*)d_ws + WS_WF_SH;

  hipLaunchKernelGGL(prep_grid,  dim3(192), dim3(256), 0, stream,
                     w0, w1, w2, wsb, xyz, gxyz, cstart);
  hipLaunchKernelGGL(px1_select, dim3(512 + NB*NS), dim3(256), 0, stream,
                     xyz, points, fps_inds, wsb, gxyz, cstart, px1, gsidx, out);
  hipLaunchKernelGGL(mlp_kernel, dim3(NB*NS/QPB), dim3(256), 0, stream,
                     xyz, fps_inds, w0, wsb, px1, gsidx, out);
}

// Round 12
// 92.108 us; speedup vs baseline: 2.1725x; 1.1508x over previous
//
#include <hip/hip_runtime.h>

#define NB 8
#define NN 4096
#define NS 1024
#define NC 64
#define OUT_PTS_OFF (NB*NS*3)
#define CAP2 256
#define RB 0.2f
#define QPB 4

typedef __attribute__((ext_vector_type(8))) short bf16x8;
typedef __attribute__((ext_vector_type(4))) float f32x4;
typedef unsigned long long u64;

static __device__ __forceinline__ short f2bf(float f){
  unsigned u = __float_as_uint(f);
  unsigned r = (u + 0x7FFFu + ((u>>16)&1u)) >> 16;
  return (short)r;
}
static __device__ __forceinline__ float bf2f(short s){
  return __uint_as_float(((unsigned)(unsigned short)s) << 16);
}
static __device__ __forceinline__ unsigned cvtpk(float a, float b){
  unsigned r;
  asm("v_cvt_pk_bf16_f32 %0, %1, %2" : "=v"(r) : "v"(a), "v"(b));
  return r;
}

// ws layout (bytes):
//   ushort gsidx[8192][64]        @ 0        (1 MB)
//   float4 gxyz [8][4096]         @ 1048576  (512 KB)
//   int    cstart[8][128]         @ 1572864  (4 KB)
//   short  px1  [32768][64]       @ 2097152  (4 MB)
//   short  wf   [47104]           @ 6291456  (94 KB)
#define WS_PX1_SH   1048576   // in shorts
#define WS_WF_SH    3145728   // in shorts

// ---- fused: prep_weights (blocks 0..183) + grid_build (blocks 184..191) ----
__global__ __launch_bounds__(256) void prep_grid(
    const float* __restrict__ w0, const float* __restrict__ w1,
    const float* __restrict__ w2, short* __restrict__ ws,
    const float* __restrict__ xyz, float4* __restrict__ gxyz,
    int* __restrict__ cstart)
{
  __shared__ int hist[125];
  __shared__ int base[125];
  const int tid = threadIdx.x;

  if (blockIdx.x < 184) {
    int e = blockIdx.x*256 + tid;
    if (e >= 47104) return;
    float v = 0.f;
    if (e < 6144) {
      int j=e&7, l=(e>>3)&63, nt=(e>>9)&3, kt=e>>11;
      int k = kt*32 + ((l>>4)<<3) + j, n = nt*16 + (l&15);
      if (k < 64) v = w0[(3+k)*64 + n];
      else if (k < 67) v = w0[(k-64)*64 + n];
    } else if (e < 14336) {
      int e2=e-6144;
      int j=e2&7, l=(e2>>3)&63, nt=(e2>>9)&7, kt=e2>>12;
      int k = kt*32 + ((l>>4)<<3) + j, n = nt*16 + (l&15);
      v = w1[k*128 + n];
    } else {
      // wf2 k-relabel matches fragment-ordered h2f (R9, proven)
      int e3=e-14336;
      int j=e3&7, l=(e3>>3)&63, nt=(e3>>9)&15, kt=e3>>13;
      int k = (kt*2 + (j&1))*16 + ((l>>4)<<2) + (j>>1);
      v = w2[k*256 + nt*16 + (l&15)];
    }
    ws[e] = f2bf(v);
    return;
  }

  const int b = blockIdx.x - 184;
  const float* xb = xyz + (size_t)b*NN*3;
  if (tid < 125) hist[tid] = 0;
  __syncthreads();

  float xs[16], ys[16], zs[16]; int cl[16];
  {
    const float4* xv = (const float4*)(xb + tid*48);
    #pragma unroll
    for (int g=0; g<4; ++g) {
      float4 v0 = xv[g*3], v1 = xv[g*3+1], v2 = xv[g*3+2];
      xs[g*4+0]=v0.x; xs[g*4+1]=v0.w; xs[g*4+2]=v1.z; xs[g*4+3]=v2.y;
      ys[g*4+0]=v0.y; ys[g*4+1]=v1.x; ys[g*4+2]=v1.w; ys[g*4+3]=v2.z;
      zs[g*4+0]=v0.z; zs[g*4+1]=v1.y; zs[g*4+2]=v2.x; zs[g*4+3]=v2.w;
    }
  }
  #pragma unroll
  for (int r=0; r<16; ++r) {
    int cx = min(4, (int)(xs[r]*5.0f));
    int cy = min(4, (int)(ys[r]*5.0f));
    int cz = min(4, (int)(zs[r]*5.0f));
    cl[r] = (cz*5+cy)*5+cx;
    atomicAdd(&hist[cl[r]], 1);
  }
  __syncthreads();
  if (tid == 0) {
    int acc = 0;
    for (int c=0; c<125; ++c) { base[c]=acc; cstart[b*128+c]=acc; acc+=hist[c]; }
    cstart[b*128+125] = NN;
  }
  __syncthreads();
  #pragma unroll
  for (int r=0; r<16; ++r) {
    int slot = atomicAdd(&base[cl[r]], 1);
    gxyz[b*NN + slot] = make_float4(xs[r], ys[r], zs[r], __int_as_float(tid*16+r));
  }
}

// ---- fused px1 (blocks 0..511) + wave-per-query select (blocks 512..2559) ----
__global__ __launch_bounds__(256) void px1_select(
    const float* __restrict__ xyz, const float* __restrict__ points,
    const int* __restrict__ fps_inds, const short* __restrict__ wsb,
    const float4* __restrict__ gxyz, const int* __restrict__ cstart,
    short* __restrict__ px1, unsigned short* __restrict__ gsidx,
    float* __restrict__ out)
{
  __shared__ u64 candk[4][CAP2];     // 8 KB: per-wave candidate keys (dbits<<16 | idx)
  __shared__ int tmpi[4][64];        // 1 KB
  __shared__ int segS[4][28], segB[4][28], segE[4][28];
  __shared__ int scell[126];

  const int tid = threadIdx.x;

  if (blockIdx.x < 512) {
    // ---------------- px1: 64 rows per block ----------------
    const int w = tid>>6, l = tid&63, lr = l&15, grp = l>>4;
    const int rowbase = blockIdx.x*64 + w*16;
    const int row = rowbase + lr;
    const float* prow = points + (size_t)row*NC;
    const float* xr   = xyz + (size_t)row*3;

    bf16x8 a0, a1, a2;
    {
      float4 u0 = *(const float4*)(prow + grp*8);
      float4 u1 = *(const float4*)(prow + grp*8 + 4);
      float4 u2 = *(const float4*)(prow + 32 + grp*8);
      float4 u3 = *(const float4*)(prow + 32 + grp*8 + 4);
      a0 = (bf16x8){f2bf(u0.x),f2bf(u0.y),f2bf(u0.z),f2bf(u0.w),f2bf(u1.x),f2bf(u1.y),f2bf(u1.z),f2bf(u1.w)};
      a1 = (bf16x8){f2bf(u2.x),f2bf(u2.y),f2bf(u2.z),f2bf(u2.w),f2bf(u3.x),f2bf(u3.y),f2bf(u3.z),f2bf(u3.w)};
      short e0=0,e1=0,e2v=0;
      if (grp==0) { e0=f2bf(xr[0]); e1=f2bf(xr[1]); e2v=f2bf(xr[2]); }
      a2 = (bf16x8){e0,e1,e2v,0,0,0,0,0};
    }
    f32x4 zero4 = {0.f,0.f,0.f,0.f};
    #pragma unroll
    for (int nt=0; nt<4; ++nt) {
      f32x4 acc = zero4;
      bf16x8 b0 = *(const bf16x8*)(wsb + (((0*4+nt)*64 + l)<<3));
      bf16x8 b1 = *(const bf16x8*)(wsb + (((1*4+nt)*64 + l)<<3));
      bf16x8 b2 = *(const bf16x8*)(wsb + (((2*4+nt)*64 + l)<<3));
      acc = __builtin_amdgcn_mfma_f32_16x16x32_bf16(a0, b0, acc, 0,0,0);
      acc = __builtin_amdgcn_mfma_f32_16x16x32_bf16(a1, b1, acc, 0,0,0);
      acc = __builtin_amdgcn_mfma_f32_16x16x32_bf16(a2, b2, acc, 0,0,0);
      #pragma unroll
      for (int i=0;i<4;++i)
        px1[(size_t)(rowbase + grp*4 + i)*64 + nt*16 + lr] = f2bf(acc[i]);
    }
    return;
  }

  // ---------------- select: ONE QUERY PER WAVE, no barriers ----------------
  const int sb = blockIdx.x - 512;        // 0..2047
  const int wv = tid>>6, lane = tid&63;
  const int q = sb*QPB + wv, b = q >> 10; // 4 | 1024 -> whole block same batch
  const float* xb = xyz + (size_t)b*NN*3;

  if (tid < 126) scell[tid] = cstart[b*128+tid];
  __syncthreads();                        // only barrier: scell ready

  const int fps = fps_inds[q];
  const float qx = xb[fps*3+0], qy = xb[fps*3+1], qz = xb[fps*3+2];
  if (lane < 3) out[q*3+lane] = xb[fps*3+lane];

  // segments: lanes 0..26 compute cell spans; wave prefix via shuffle
  int len = 0, s = 0;
  if (lane < 27) {
    const int cx = min(4, (int)(qx*5.0f));
    const int cy = min(4, (int)(qy*5.0f));
    const int cz = min(4, (int)(qz*5.0f));
    int ncx = cx + lane%3 - 1, ncy = cy + (lane/3)%3 - 1, ncz = cz + lane/9 - 1;
    if (ncx>=0 && ncx<5 && ncy>=0 && ncy<5 && ncz>=0 && ncz<5) {
      float lox = ncx*0.2f - 1e-5f, hix = lox + 0.2f + 2e-5f;
      float loy = ncy*0.2f - 1e-5f, hiy = loy + 0.2f + 2e-5f;
      float loz = ncz*0.2f - 1e-5f, hiz = loz + 0.2f + 2e-5f;
      float dx = fmaxf(0.f, fmaxf(lox-qx, qx-hix));
      float dy = fmaxf(0.f, fmaxf(loy-qy, qy-hiy));
      float dz = fmaxf(0.f, fmaxf(loz-qz, qz-hiz));
      if (fmaf(dx,dx, fmaf(dy,dy, dz*dz)) <= 0.0402f) {
        int c = (ncz*5+ncy)*5+ncx;
        s = scell[c]; len = scell[c+1] - s;
      }
    }
  }
  int incl = len;
  #pragma unroll
  for (int off=1; off<64; off<<=1) {
    int v = __shfl_up(incl, off, 64);
    if (lane >= off) incl += v;
  }
  const int T = __shfl(incl, 26, 64);
  if (lane < 27) { segS[wv][lane]=s; segB[wv][lane]=incl-len; segE[wv][lane]=incl; }
  __builtin_amdgcn_wave_barrier();

  // gather + ballot compaction (wave-synchronous, no atomics)
  const float4* gb = gxyz + b*NN;
  int base = 0, k = 0;
  const int rounds = (T + 63) >> 6;
  const u64 ltmask = (1ull << lane) - 1ull;
  for (int r = 0; r < rounds; ++r) {
    int t = r*64 + lane;
    bool hit = false; u64 key = 0;
    if (t < T) {
      while (t >= segE[wv][k]) ++k;
      float4 p = gb[segS[wv][k] + (t - segB[wv][k])];
      float fx = qx-p.x, fy = qy-p.y, fz = qz-p.z;
      float ff = fmaf(fx,fx, fmaf(fy,fy, fz*fz));
      if (ff < 0.0402f) {
        float dx=__fsub_rn(qx,p.x), dy=__fsub_rn(qy,p.y), dz=__fsub_rn(qz,p.z);
        float d2=__fadd_rn(__fadd_rn(__fmul_rn(dx,dx),__fmul_rn(dy,dy)),__fmul_rn(dz,dz));
        float d = __fsqrt_rn(d2);
        if (d < RB) {
          hit = true;
          key = ((u64)__float_as_uint(d) << 16) | (u64)(unsigned)__float_as_int(p.w);
        }
      }
    }
    u64 m = __ballot(hit);
    int pos = base + (int)__popcll(m & ltmask);
    if (hit && pos < CAP2) candk[wv][pos] = key;
    base += (int)__popcll(m);
  }
  int cnt = base < CAP2 ? base : CAP2;
  __builtin_amdgcn_wave_barrier();

  if (cnt > 64) {
    // rank by u64 key == (dist, idx) lexicographic; keys unique
    for (int j = lane; j < cnt; j += 64) {
      u64 kj = candk[wv][j];
      int rk = 0;
      for (int i = 0; i < cnt; ++i) rk += (int)(candk[wv][i] < kj);
      if (rk < 64) tmpi[wv][rk] = (int)(kj & 0xFFFFu);
    }
    __builtin_amdgcn_wave_barrier();
    int v = tmpi[wv][lane];
    int p = 0;
    #pragma unroll 8
    for (int u = 0; u < 64; ++u) p += (int)(tmpi[wv][u] < v);
    gsidx[q*64 + p] = (unsigned short)v;
  } else {
    if (lane < cnt) {
      int v = (int)(candk[wv][lane] & 0xFFFFu);
      int p = 0;
      for (int u = 0; u < cnt; ++u) p += (int)((int)(candk[wv][u] & 0xFFFFu) < v);
      tmpi[wv][p] = v;
    }
    __builtin_amdgcn_wave_barrier();
    gsidx[q*64 + lane] = (unsigned short)tmpi[wv][lane < cnt ? lane : 0];
  }
}

// ---- MLP: persistent QPB queries/block; wf2 in regs, wf1 in LDS (R9/R11 proven) ----
// launch_bounds (256,2): DO NOT raise — (256,4) spilled b3 (R6: VGPR=64, 139us).
__global__ __launch_bounds__(256,2) void mlp_kernel(
    const float* __restrict__ xyz, const int* __restrict__ fps_inds,
    const float* __restrict__ w0, const short* __restrict__ wsb,
    const short* __restrict__ px1, const unsigned short* __restrict__ gsidx,
    float* __restrict__ out)
{
  __shared__ __align__(16) short w1s[8192];   // 16 KB
  __shared__ __align__(16) short h2f[8192];   // 16 KB, fragment-ordered
  __shared__ float q1s[QPB][64];
  __shared__ int sidx[QPB][64];

  const int tid = threadIdx.x;
  const int w = tid>>6, l = tid&63, lr = l&15, grp = l>>4;
  const int q0 = blockIdx.x*QPB;
  const int b = q0 >> 10;
  const float* xb = xyz + (size_t)b*NN*3;

  bf16x8 b3[4][4];
  #pragma unroll
  for (int kt=0; kt<4; ++kt)
    #pragma unroll
    for (int j=0; j<4; ++j)
      b3[kt][j] = *(const bf16x8*)(wsb + 14336 + (((kt*16 + w*4 + j)*64 + l)<<3));

  #pragma unroll
  for (int e = 0; e < 4; ++e) {
    int s = tid + e*256;
    *(bf16x8*)&w1s[s*8] = *(const bf16x8*)(wsb + 6144 + s*8);
  }
  {
    int qq = tid>>6, t = tid&63;   // 256 threads = QPB*64 exactly
    int fp = fps_inds[q0+qq];
    sidx[qq][t] = (int)gsidx[(q0+qq)*64 + t];
    q1s[qq][t] = xb[fp*3]*w0[t] + xb[fp*3+1]*w0[64+t] + xb[fp*3+2]*w0[128+t];
  }
  if (tid < QPB*3) {
    int qq = tid/3, c = tid - qq*3;
    int fp = fps_inds[q0+qq];
    out[(q0+qq)*3 + c] = xb[fp*3+c];
  }
  __syncthreads();

  const short* px1b = px1 + (size_t)b*NN*64;
  const int myrow = w*16 + lr;

  bf16x8 v0, v1;
  {
    int idx = sidx[0][myrow];
    v0 = *(const bf16x8*)(px1b + idx*64 + grp*8);
    v1 = *(const bf16x8*)(px1b + idx*64 + 32 + grp*8);
  }

  f32x4 zero4 = {0.f,0.f,0.f,0.f};
  const int uu4 = (lr>>2) << 4;     // write-side XOR (byte bits 4-5)
  const int gg4 = grp << 4;         // read-side XOR

  for (int qq = 0; qq < QPB; ++qq) {
    if (qq) __syncthreads();

    bf16x8 a20, a21;
    {
      union { unsigned u[4]; bf16x8 v; } ua, ub;
      #pragma unroll
      for (int jp=0; jp<4; ++jp) {
        float x0 = fmaxf(bf2f(v0[2*jp  ]) - q1s[qq][grp*8+2*jp  ], 0.f);
        float x1 = fmaxf(bf2f(v0[2*jp+1]) - q1s[qq][grp*8+2*jp+1], 0.f);
        ua.u[jp] = cvtpk(x0, x1);
        float y0 = fmaxf(bf2f(v1[2*jp  ]) - q1s[qq][32+grp*8+2*jp  ], 0.f);
        float y1 = fmaxf(bf2f(v1[2*jp+1]) - q1s[qq][32+grp*8+2*jp+1], 0.f);
        ub.u[jp] = cvtpk(y0, y1);
      }
      a20 = ua.v; a21 = ub.v;
    }
    if (qq+1 < QPB) {
      int idx = sidx[qq+1][myrow];
      v0 = *(const bf16x8*)(px1b + idx*64 + grp*8);
      v1 = *(const bf16x8*)(px1b + idx*64 + 32 + grp*8);
    }

    #pragma unroll
    for (int ntp=0; ntp<4; ++ntp) {
      f32x4 accA = zero4, accB = zero4;
      bf16x8 bA0 = *(const bf16x8*)&w1s[((0*8 + 2*ntp  )*64 + l)*8];
      bf16x8 bA1 = *(const bf16x8*)&w1s[((1*8 + 2*ntp  )*64 + l)*8];
      bf16x8 bB0 = *(const bf16x8*)&w1s[((0*8 + 2*ntp+1)*64 + l)*8];
      bf16x8 bB1 = *(const bf16x8*)&w1s[((1*8 + 2*ntp+1)*64 + l)*8];
      accA = __builtin_amdgcn_mfma_f32_16x16x32_bf16(a20, bA0, accA, 0,0,0);
      accA = __builtin_amdgcn_mfma_f32_16x16x32_bf16(a21, bA1, accA, 0,0,0);
      accB = __builtin_amdgcn_mfma_f32_16x16x32_bf16(a20, bB0, accB, 0,0,0);
      accB = __builtin_amdgcn_mfma_f32_16x16x32_bf16(a21, bB1, accB, 0,0,0);
      #pragma unroll
      for (int i=0; i<4; ++i) {
        unsigned pv = cvtpk(fmaxf(accA[i],0.f), fmaxf(accB[i],0.f));
        int byteoff = ((((w*4+ntp)*64 + (lr>>2)*16 + grp*4 + i)<<4) + ((lr&3)<<2)) ^ uu4;
        *(unsigned*)((char*)h2f + byteoff) = pv;
      }
    }
    __syncthreads();

    // layer 3: running-max over mt
    float rm[4][4];
    #pragma unroll
    for (int j=0;j<4;++j)
      #pragma unroll
      for (int i=0;i<4;++i) rm[j][i] = 0.f;
    #pragma unroll
    for (int mt=0; mt<4; ++mt) {
      f32x4 acc[4] = {zero4, zero4, zero4, zero4};
      #pragma unroll
      for (int kt=0; kt<4; ++kt) {
        int byteoff = ((((mt*4+kt)*64 + l)<<4)) ^ gg4;
        bf16x8 a = *(const bf16x8*)((const char*)h2f + byteoff);
        #pragma unroll
        for (int j=0; j<4; ++j)
          acc[j] = __builtin_amdgcn_mfma_f32_16x16x32_bf16(a, b3[kt][j], acc[j], 0,0,0);
      }
      #pragma unroll
      for (int j=0; j<4; ++j)
        #pragma unroll
        for (int i=0; i<4; ++i) rm[j][i] = fmaxf(rm[j][i], acc[j][i]);
    }
    #pragma unroll
    for (int j=0; j<4; ++j) {
      float m = fmaxf(fmaxf(rm[j][0],rm[j][1]), fmaxf(rm[j][2],rm[j][3]));
      m = fmaxf(m, __shfl_xor(m, 16, 64));
      m = fmaxf(m, __shfl_xor(m, 32, 64));
      if (grp == 0) out[OUT_PTS_OFF + (q0+qq)*256 + (w*4+j)*16 + lr] = m;
    }
  }
}

extern "C" void kernel_launch(void* const* d_in, const int* in_sizes, int n_in,
                              void* d_out, int out_size, void* d_ws, size_t ws_size,
                              hipStream_t stream) {
  const float* xyz      = (const float*)d_in[0];
  const float* points   = (const float*)d_in[1];
  const int*   fps_inds = (const int*)d_in[2];
  const float* w0       = (const float*)d_in[3];
  const float* w1       = (const float*)d_in[4];
  const float* w2       = (const float*)d_in[5];
  float* out = (float*)d_out;

  unsigned short* gsidx = (unsigned short*)d_ws;
  float4* gxyz  = (float4*)((char*)d_ws + 1048576);
  int*    cstart= (int*)((char*)d_ws + 1572864);
  short*  px1   = (short*)d_ws + WS_PX1_SH;
  short*  wsb   = (short*)d_ws + WS_WF_SH;

  hipLaunchKernelGGL(prep_grid,  dim3(192), dim3(256), 0, stream,
                     w0, w1, w2, wsb, xyz, gxyz, cstart);
  hipLaunchKernelGGL(px1_select, dim3(512 + NB*NS/QPB), dim3(256), 0, stream,
                     xyz, points, fps_inds, wsb, gxyz, cstart, px1, gsidx, out);
  hipLaunchKernelGGL(mlp_kernel, dim3(NB*NS/QPB), dim3(256), 0, stream,
                     xyz, fps_inds, w0, wsb, px1, gsidx, out);
}